// Round 3
// baseline (239.312 us; speedup 1.0000x reference)
//
#include <hip/hip_runtime.h>
#include <hip/hip_bf16.h>

// Model dims (fixed by the problem)
#define BB    2
#define TT    128
#define CC    64
#define HH    4
#define SS    16
#define D4    256     // 4*C
#define HID_  256
#define VV    32000
#define NPE_  4
#define RR    256     // B*T

using bf16 = __hip_bfloat16;
using InT  = float;  // fp32 inputs (npz size; no bf16 eps floor in threshold)
using OutT = float;  // fp32 output (reference returns jnp.float32; pure-relative threshold)

__device__ __forceinline__ float cvt(float v) { return v; }
__device__ __forceinline__ OutT ocvt(float v) { return v; }

__device__ __forceinline__ float wred_sum(float v) {
#pragma unroll
    for (int off = 32; off; off >>= 1) v += __shfl_xor(v, off, 64);
    return v;
}
__device__ __forceinline__ float wred_max(float v) {
#pragma unroll
    for (int off = 32; off; off >>= 1) v = fmaxf(v, __shfl_xor(v, off, 64));
    return v;
}
__device__ __forceinline__ float sigm(float x) { return 1.f / (1.f + __expf(-x)); }

// -------- embed: x[r][c] = tok_emb[idx[r]][c] --------
__global__ void k_embed(const int* __restrict__ idx, const InT* __restrict__ tok,
                        float* __restrict__ x) {
    int r = blockIdx.x, c = threadIdx.x;
    x[r * CC + c] = cvt(tok[idx[r] * CC + c]);
}

// -------- positional embeddings for all 4 p: pos[p][t][c] --------
__global__ void k_pos(const InT* __restrict__ pe_tab, const InT* __restrict__ W1,
                      const InT* __restrict__ b1, const InT* __restrict__ W2,
                      const InT* __restrict__ b2, const InT* __restrict__ g,
                      const InT* __restrict__ bb, float* __restrict__ pos) {
    int p = blockIdx.x >> 7, t = blockIdx.x & 127, c = threadIdx.x;
    __shared__ float s_pe[CC], s_h[CC];
    s_pe[c] = cvt(pe_tab[(p * TT + t) * CC + c]);
    __syncthreads();
    const InT* w1 = W1 + p * CC * CC;
    float a = cvt(b1[p * CC + c]);
    for (int k = 0; k < CC; k++) a += s_pe[k] * cvt(w1[k * CC + c]);
    s_h[c] = sigm(a);
    __syncthreads();
    const InT* w2 = W2 + p * CC * CC;
    float o = cvt(b2[p * CC + c]);
    for (int k = 0; k < CC; k++) o += s_h[k] * cvt(w2[k * CC + c]);
    float m = wred_sum(o) * (1.f / CC);
    float d = o - m;
    float var = wred_sum(d * d) * (1.f / CC);
    pos[(p * TT + t) * CC + c] =
        d * rsqrtf(var + 1e-5f) * cvt(g[p * CC + c]) + cvt(bb[p * CC + c]);
}

// -------- LN1 + per-head value projection --------
__global__ void k_ln1v(const float* __restrict__ x, const InT* __restrict__ g,
                       const InT* __restrict__ b, const InT* __restrict__ valW,
                       float* __restrict__ xn, float* __restrict__ v) {
    int r = blockIdx.x, c = threadIdx.x;
    __shared__ float s[CC];
    float xv = x[r * CC + c];
    float m = wred_sum(xv) * (1.f / CC);
    float d = xv - m;
    float var = wred_sum(d * d) * (1.f / CC);
    float y = d * rsqrtf(var + 1e-5f) * cvt(g[c]) + cvt(b[c]);
    xn[r * CC + c] = y;
    s[c] = y;
    __syncthreads();
    int h = c >> 4, sd = c & 15;
    const InT* w = valW + h * CC * SS;
    float acc = 0.f;
    for (int k = 0; k < CC; k++) acc += s[k] * cvt(w[k * SS + sd]);
    v[(h * RR + r) * SS + sd] = acc;
}

// -------- K/Q projections: Kp/Qp[h][row][d] = sum_c x1[row][c] * W1[h][c(+128)][d] --------
__global__ void k_kq(const float* __restrict__ pos_p, const float* __restrict__ xn,
                     const InT* __restrict__ attW1, float* __restrict__ Kp,
                     float* __restrict__ Qp) {
    // blockIdx.x = [h(4)][kq(2)][rg(32)], 8 rows per block, 256 threads = 256 output cols
    int rg = blockIdx.x & 31, kq = (blockIdx.x >> 5) & 1, h = blockIdx.x >> 6;
    int r0 = rg * 8;
    __shared__ float x1[8][128];
    int tid = threadIdx.x;
    for (int e = tid; e < 8 * 128; e += 256) {
        int rr = e >> 7, cc = e & 127;
        int row = r0 + rr, t = row & (TT - 1);
        x1[rr][cc] = (cc < CC) ? pos_p[t * CC + cc] : xn[row * CC + (cc - CC)];
    }
    __syncthreads();
    const InT* w = attW1 + (h * D4 + kq * 128) * D4;
    int d = tid;
    float acc[8] = {0, 0, 0, 0, 0, 0, 0, 0};
    for (int c = 0; c < 128; c++) {
        float wv = cvt(w[c * D4 + d]);
#pragma unroll
        for (int rr = 0; rr < 8; rr++) acc[rr] += x1[rr][c] * wv;
    }
    float* out = kq ? Qp : Kp;
#pragma unroll
    for (int rr = 0; rr < 8; rr++) out[(h * RR + r0 + rr) * D4 + d] = acc[rr];
}

// -------- attention: scores via sigmoid-MLP, softmax, weighted V --------
__global__ void __launch_bounds__(256) k_attn(
    const float* __restrict__ Kp, const float* __restrict__ Qp,
    const InT* __restrict__ ab1, const InT* __restrict__ aw2,
    const InT* __restrict__ ab2, const float* __restrict__ v,
    float* __restrict__ o) {
    int h = blockIdx.x >> 8, row = blockIdx.x & 255;
    int b = row >> 7, i = row & 127;
    __shared__ __align__(16) float q_s[D4];
    __shared__ __align__(16) float w2_s[D4];
    __shared__ float sc[TT];
    __shared__ float part[16][17];
    int tid = threadIdx.x;
    q_s[tid] = Qp[(h * RR + row) * D4 + tid] + cvt(ab1[h * D4 + tid]);
    w2_s[tid] = cvt(aw2[h * D4 + tid]);
    __syncthreads();
    int wv = tid >> 6, lane = tid & 63;
    const float* Kbase = Kp + (h * RR + b * TT) * D4;
    float4 qq = *(const float4*)(q_s + lane * 4);
    float4 ww = *(const float4*)(w2_s + lane * 4);
    float b2s = cvt(ab2[h]);
    for (int j = wv; j <= i; j += 4) {
        float4 kk = *(const float4*)(Kbase + j * D4 + lane * 4);
        float a = sigm(qq.x + kk.x) * ww.x + sigm(qq.y + kk.y) * ww.y +
                  sigm(qq.z + kk.z) * ww.z + sigm(qq.w + kk.w) * ww.w;
        a = wred_sum(a);
        if (lane == 0) sc[j] = (a + b2s) * 0.125f;  // * C^-0.5
    }
    __syncthreads();
    if (tid < 64) {
        float s0 = (tid <= i) ? sc[tid] : -1e30f;
        float s1 = (tid + 64 <= i) ? sc[tid + 64] : -1e30f;
        float m = wred_max(fmaxf(s0, s1));
        float e0 = (tid <= i) ? __expf(s0 - m) : 0.f;
        float e1 = (tid + 64 <= i) ? __expf(s1 - m) : 0.f;
        float inv = 1.f / wred_sum(e0 + e1);
        sc[tid] = e0 * inv;
        sc[tid + 64] = e1 * inv;
    }
    __syncthreads();
    int s = tid & 15, gidx = tid >> 4;
    const float* vb = v + (h * RR + b * TT) * SS;
    float acc = 0.f;
    for (int j = gidx; j <= i; j += 16) acc += sc[j] * vb[j * SS + s];
    part[gidx][s] = acc;
    __syncthreads();
    if (tid < 16) {
        float a = 0.f;
#pragma unroll
        for (int gg = 0; gg < 16; gg++) a += part[gg][tid];
        o[row * CC + h * SS + tid] = a;
    }
}

// -------- proj + residual + LN2 + FF + residual + LN3 --------
__global__ void k_post(float* __restrict__ x, const float* __restrict__ o,
                       const InT* __restrict__ projW, const InT* __restrict__ projb,
                       const InT* __restrict__ g2, const InT* __restrict__ b2,
                       const InT* __restrict__ fW1, const InT* __restrict__ fb1,
                       const InT* __restrict__ fW2, const InT* __restrict__ fb2,
                       const InT* __restrict__ g3, const InT* __restrict__ b3) {
    int r = blockIdx.x, c = threadIdx.x;
    __shared__ float s_o[CC], s_h[HID_], s_x[CC];
    s_o[c] = o[r * CC + c];
    __syncthreads();
    float acc = cvt(projb[c]);
    for (int k = 0; k < CC; k++) acc += s_o[k] * cvt(projW[k * CC + c]);
    float xv = x[r * CC + c] + acc;
    float m = wred_sum(xv) * (1.f / CC);
    float d = xv - m;
    float var = wred_sum(d * d) * (1.f / CC);
    float y = d * rsqrtf(var + 1e-5f) * cvt(g2[c]) + cvt(b2[c]);
    s_x[c] = y;
    __syncthreads();
#pragma unroll
    for (int u = 0; u < 4; u++) {
        int hc = u * CC + c;
        float a = cvt(fb1[hc]);
        for (int k = 0; k < CC; k++) a += s_x[k] * cvt(fW1[k * HID_ + hc]);
        s_h[hc] = sigm(a);
    }
    __syncthreads();
    float f = cvt(fb2[c]);
    for (int k = 0; k < HID_; k++) f += s_h[k] * cvt(fW2[k * CC + c]);
    xv += f;
    m = wred_sum(xv) * (1.f / CC);
    d = xv - m;
    var = wred_sum(d * d) * (1.f / CC);
    x[r * CC + c] = d * rsqrtf(var + 1e-5f) * cvt(g3[c]) + cvt(b3[c]);
}

// -------- lm_head: out[r][v] = x[r] . lm_W[:,v] + lm_b[v] --------
__global__ void __launch_bounds__(256) k_lmhead(const float* __restrict__ x,
                                                const InT* __restrict__ lmW,
                                                const InT* __restrict__ lmb,
                                                OutT* __restrict__ out) {
    int v = blockIdx.x * 256 + threadIdx.x;
    int r0 = blockIdx.y * 64;
    __shared__ float xs[64][CC];
    for (int e = threadIdx.x; e < 64 * CC; e += 256) {
        int rr = e >> 6, cc = e & 63;
        xs[rr][cc] = x[(r0 + rr) * CC + cc];
    }
    __syncthreads();
    float w[CC];
#pragma unroll
    for (int c = 0; c < CC; c++) w[c] = cvt(lmW[c * VV + v]);
    float bias = cvt(lmb[v]);
    for (int rr = 0; rr < 64; rr++) {
        float a = bias;
#pragma unroll
        for (int c = 0; c < CC; c++) a += xs[rr][c] * w[c];
        out[(r0 + rr) * VV + v] = ocvt(a);
    }
}

extern "C" void kernel_launch(void* const* d_in, const int* in_sizes, int n_in,
                              void* d_out, int out_size, void* d_ws, size_t ws_size,
                              hipStream_t stream) {
    const int* idx   = (const int*)d_in[0];
    const InT* tok   = (const InT*)d_in[1];
    const InT* petab = (const InT*)d_in[2];
    const InT* peW1  = (const InT*)d_in[3];
    const InT* peb1  = (const InT*)d_in[4];
    const InT* peW2  = (const InT*)d_in[5];
    const InT* peb2  = (const InT*)d_in[6];
    const InT* peg   = (const InT*)d_in[7];
    const InT* pebb  = (const InT*)d_in[8];
    const InT* ln1g  = (const InT*)d_in[9];
    const InT* ln1b  = (const InT*)d_in[10];
    const InT* attW1 = (const InT*)d_in[11];
    const InT* attb1 = (const InT*)d_in[12];
    const InT* attW2 = (const InT*)d_in[13];
    const InT* attb2 = (const InT*)d_in[14];
    const InT* valW  = (const InT*)d_in[15];
    const InT* projW = (const InT*)d_in[16];
    const InT* projb = (const InT*)d_in[17];
    const InT* ln2g  = (const InT*)d_in[18];
    const InT* ln2b  = (const InT*)d_in[19];
    const InT* ffW1  = (const InT*)d_in[20];
    const InT* ffb1  = (const InT*)d_in[21];
    const InT* ffW2  = (const InT*)d_in[22];
    const InT* ffb2  = (const InT*)d_in[23];
    const InT* ln3g  = (const InT*)d_in[24];
    const InT* ln3b  = (const InT*)d_in[25];
    const InT* lmW   = (const InT*)d_in[26];
    const InT* lmb   = (const InT*)d_in[27];

    float* ws  = (float*)d_ws;
    float* x   = ws;                 // 256*64        = 16384
    float* xn  = ws + 16384;         // 256*64        = 16384
    float* pos = ws + 32768;         // 4*128*64      = 32768
    float* v   = ws + 65536;         // 4*256*16      = 16384
    float* o   = ws + 81920;         // 256*64        = 16384
    float* Kp  = ws + 98304;         // 4*256*256     = 262144
    float* Qp  = ws + 360448;        // 4*256*256     = 262144

    k_embed<<<RR, CC, 0, stream>>>(idx, tok, x);
    k_pos<<<NPE_ * TT, CC, 0, stream>>>(petab, peW1, peb1, peW2, peb2, peg, pebb, pos);
    for (int p = 0; p < NPE_; p++) {
        k_ln1v<<<RR, CC, 0, stream>>>(x, ln1g, ln1b, valW, xn, v);
        k_kq<<<256, 256, 0, stream>>>(pos + p * TT * CC, xn, attW1, Kp, Qp);
        k_attn<<<HH * RR, 256, 0, stream>>>(Kp, Qp, attb1, attW2, attb2, v, o);
        k_post<<<RR, CC, 0, stream>>>(x, o, projW, projb, ln2g, ln2b, ffW1, ffb1,
                                      ffW2, ffb2, ln3g, ln3b);
    }
    k_lmhead<<<dim3(VV / 256, RR / 64), 256, 0, stream>>>(x, lmW, lmb, (OutT*)d_out);
}